// Round 3
// baseline (219.528 us; speedup 1.0000x reference)
//
#include <hip/hip_runtime.h>

// MHA: B=4, S=2048, D_MODEL=512, H=8, D_HEAD=64
// Wt transpose -> QKV proj GEMMs (one launch) -> flash attn (swapped-MFMA,
// in-register softmax, defer-max, async-stage) -> out proj GEMM

typedef unsigned short u16;
typedef __bf16 bf16x8 __attribute__((ext_vector_type(8)));
typedef float  f32x4  __attribute__((ext_vector_type(4)));

__device__ __forceinline__ u16 f2bf(float x) {
  unsigned u = __float_as_uint(x);
  u += 0x7fffu + ((u >> 16) & 1u);   // RNE
  return (u16)(u >> 16);
}

__device__ __forceinline__ unsigned cvtpk(float lo, float hi) {
  unsigned r;
  asm("v_cvt_pk_bf16_f32 %0, %1, %2" : "=v"(r) : "v"(lo), "v"(hi));
  return r;
}

__device__ __forceinline__ f32x4 mfma16(bf16x8 a, bf16x8 b, f32x4 c) {
  return __builtin_amdgcn_mfma_f32_16x16x32_bf16(a, b, c, 0, 0, 0);
}

// ---- W[k][n] fp32 -> Wt[n][k] bf16, all 4 weights in one launch ----
__global__ __launch_bounds__(256) void wtrans_k(const float* __restrict__ W0,
                                                const float* __restrict__ W1,
                                                const float* __restrict__ W2,
                                                const float* __restrict__ W3,
                                                u16* __restrict__ Wt) {
  int sel = blockIdx.y;
  const float* W = sel == 0 ? W0 : sel == 1 ? W1 : sel == 2 ? W2 : W3;
  int idx = blockIdx.x * 256 + threadIdx.x;
  int k = idx >> 9, n = idx & 511;
  Wt[sel * 262144 + n * 512 + k] = f2bf(W[idx]);
}

// ---- GEMM body: A[8192x512] @ Bt^T + bias (Bt is [n][k] bf16) ----
// OUT_MODE: 0 bf16 [m][n], 1 bf16 vT[(b*8+h)*64+d][s], 2 fp32 [m][n]
template <bool A_BF16, int OUT_MODE>
__device__ __forceinline__ void gemm_body(const void* __restrict__ Ap,
                                          const u16* __restrict__ Bt,
                                          const float* __restrict__ bias,
                                          void* __restrict__ outp, int bidx) {
  __shared__ __align__(16) u16 As[128][72];
  __shared__ __align__(16) u16 Bs[128][72];
  int tid = threadIdx.x;
  int lane = tid & 63, wid = tid >> 6;
  int wm = wid >> 1, wn = wid & 1;
  int lr = lane & 15, lg = lane >> 4;
  int bm = bidx >> 2, bn = bidx & 3;

  f32x4 acc[4][4];
#pragma unroll
  for (int i = 0; i < 4; ++i)
#pragma unroll
    for (int j = 0; j < 4; ++j) {
      f32x4 z = {0.f, 0.f, 0.f, 0.f};
      acc[i][j] = z;
    }

  for (int kt = 0; kt < 8; ++kt) {
    int k0 = kt * 64;
    if (!A_BF16) {
      const float* A = (const float*)Ap;
#pragma unroll
      for (int i = 0; i < 8; ++i) {
        int idx = i * 256 + tid;
        int row = idx >> 4, c4 = idx & 15;
        float4 v = *(const float4*)(A + (size_t)(bm * 128 + row) * 512 + k0 + c4 * 4);
        ushort4 pk = make_ushort4(f2bf(v.x), f2bf(v.y), f2bf(v.z), f2bf(v.w));
        *(ushort4*)&As[row][c4 * 4] = pk;
      }
    } else {
      const u16* A = (const u16*)Ap;
#pragma unroll
      for (int i = 0; i < 4; ++i) {
        int idx = i * 256 + tid;
        int row = idx >> 3, c8 = idx & 7;
        uint4 v = *(const uint4*)(A + (size_t)(bm * 128 + row) * 512 + k0 + c8 * 8);
        *(uint4*)&As[row][c8 * 8] = v;
      }
    }
#pragma unroll
    for (int i = 0; i < 4; ++i) {
      int idx = i * 256 + tid;
      int row = idx >> 3, c8 = idx & 7;
      uint4 v = *(const uint4*)(Bt + (size_t)(bn * 128 + row) * 512 + k0 + c8 * 8);
      *(uint4*)&Bs[row][c8 * 8] = v;
    }
    __syncthreads();
#pragma unroll
    for (int kk = 0; kk < 2; ++kk) {
      bf16x8 af[4], bfr[4];
#pragma unroll
      for (int mf = 0; mf < 4; ++mf)
        af[mf] = *(const bf16x8*)&As[wm * 64 + mf * 16 + lr][kk * 32 + lg * 8];
#pragma unroll
      for (int nf = 0; nf < 4; ++nf)
        bfr[nf] = *(const bf16x8*)&Bs[wn * 64 + nf * 16 + lr][kk * 32 + lg * 8];
#pragma unroll
      for (int mf = 0; mf < 4; ++mf)
#pragma unroll
        for (int nf = 0; nf < 4; ++nf)
          acc[mf][nf] = mfma16(af[mf], bfr[nf], acc[mf][nf]);
    }
    __syncthreads();
  }

#pragma unroll
  for (int mf = 0; mf < 4; ++mf) {
#pragma unroll
    for (int nf = 0; nf < 4; ++nf) {
      int m = bm * 128 + wm * 64 + mf * 16 + lg * 4;
      int n = bn * 128 + wn * 64 + nf * 16 + lr;
      float bia = bias[n];
      if (OUT_MODE == 0) {
        u16* o = (u16*)outp;
#pragma unroll
        for (int r = 0; r < 4; ++r)
          o[(size_t)(m + r) * 512 + n] = f2bf(acc[mf][nf][r] + bia);
      } else if (OUT_MODE == 2) {
        float* o = (float*)outp;
#pragma unroll
        for (int r = 0; r < 4; ++r)
          o[(size_t)(m + r) * 512 + n] = acc[mf][nf][r] + bia;
      } else {
        u16* o = (u16*)outp;
        int b = m >> 11, s = m & 2047;
        int h = n >> 6, d = n & 63;
        ushort4 pk = make_ushort4(f2bf(acc[mf][nf][0] + bia), f2bf(acc[mf][nf][1] + bia),
                                  f2bf(acc[mf][nf][2] + bia), f2bf(acc[mf][nf][3] + bia));
        *(ushort4*)&o[(size_t)((b * 8 + h) * 64 + d) * 2048 + s] = pk;
      }
    }
  }
}

// QKV projections in one launch: blockIdx.y selects Q/K/V
__global__ __launch_bounds__(256) void qkv_k(const float* __restrict__ Q,
                                             const float* __restrict__ K,
                                             const float* __restrict__ V,
                                             const u16* __restrict__ Wt,   // 3 weights consecutive
                                             const float* __restrict__ bq,
                                             const float* __restrict__ bk,
                                             const float* __restrict__ bv,
                                             u16* __restrict__ outbase) {  // qws,kws,vTw consecutive
  int sel = blockIdx.y;
  const float* A = sel == 0 ? Q : sel == 1 ? K : V;
  const float* bia = sel == 0 ? bq : sel == 1 ? bk : bv;
  const u16* Bt = Wt + (size_t)sel * 262144;
  u16* out = outbase + (size_t)sel * 8192 * 512;
  if (sel == 2)
    gemm_body<false, 1>(A, Bt, bia, out, blockIdx.x);
  else
    gemm_body<false, 0>(A, Bt, bia, out, blockIdx.x);
}

__global__ __launch_bounds__(256) void gemm_out_k(const void* __restrict__ Ap,
                                                  const u16* __restrict__ Bt,
                                                  const float* __restrict__ bias,
                                                  void* __restrict__ outp) {
  gemm_body<true, 2>(Ap, Bt, bias, outp, blockIdx.x);
}

// ---- flash attention, fully swapped orientation ----
// S^T = mfma(K,Q): lane owns q = lane&15, keys nf*16+lg*4+r -> in-register softmax.
// O^T = mfma(V,P): oacc q-index = lane&15 too -> per-lane m/l, no shuffles.
// q,k bf16 [B*S][512]; vT bf16 [(b*8+h)*64+d][2048]; z bf16 [B*S][512]
__global__ __launch_bounds__(256, 4) void attn_k(const u16* __restrict__ q,
                                                 const u16* __restrict__ kmat,
                                                 const u16* __restrict__ vT,
                                                 u16* __restrict__ z) {
  __shared__ __align__(16) u16 Ks[64][64];      // [key][d], XOR swizzled
  __shared__ __align__(16) u16 Vs[64][64];      // [d][key], XOR swizzled
  __shared__ __align__(16) u16 Ps[4][16][72];   // per-wave P[q][key], padded stride
  const float C = 0.125f * 1.44269504f;         // 1/sqrt(64) * log2(e)
  int tid = threadIdx.x;
  int lane = tid & 63, w = tid >> 6;
  int lr = lane & 15, lg = lane >> 4;
  int bh = blockIdx.x >> 5, qt = blockIdx.x & 31;
  int b = bh >> 3, h = bh & 7;
  size_t qrow0 = (size_t)(b * 2048 + qt * 64 + w * 16);

  // Q as B-fragment: lane holds Q[q=lr][d = kf*32 + lg*8 + j]
  bf16x8 qf[2];
#pragma unroll
  for (int kf = 0; kf < 2; ++kf)
    qf[kf] = *(const bf16x8*)&q[(qrow0 + lr) * 512 + h * 64 + kf * 32 + lg * 8];

  f32x4 oacc[4];
#pragma unroll
  for (int j = 0; j < 4; ++j) {
    f32x4 zf = {0.f, 0.f, 0.f, 0.f};
    oacc[j] = zf;
  }
  float m = -1e30f, l = 0.f, negmC = 0.f;

  const u16* kbase = kmat + (size_t)(b * 2048) * 512 + h * 64;
  const u16* vbase = vT + (size_t)(bh * 64) * 2048;

  // staging registers (T14 async split: load early, ds_write late)
  uint4 kld[2], vld[2];
#pragma unroll
  for (int i = 0; i < 2; ++i) {
    int idx = i * 256 + tid;
    int row = idx >> 3, c8 = idx & 7;
    kld[i] = *(const uint4*)&kbase[(size_t)row * 512 + c8 * 8];
    vld[i] = *(const uint4*)&vbase[(size_t)row * 2048 + c8 * 8];
  }

  for (int kt = 0; kt < 32; ++kt) {
    // write staged tile, then issue next tile's loads
#pragma unroll
    for (int i = 0; i < 2; ++i) {
      int idx = i * 256 + tid;
      int row = idx >> 3, c8 = idx & 7;
      int sc = (c8 * 8) ^ ((row & 7) << 3);
      *(uint4*)&Ks[row][sc] = kld[i];
      *(uint4*)&Vs[row][sc] = vld[i];
    }
    __syncthreads();
    if (kt < 31) {
#pragma unroll
      for (int i = 0; i < 2; ++i) {
        int idx = i * 256 + tid;
        int row = idx >> 3, c8 = idx & 7;
        kld[i] = *(const uint4*)&kbase[(size_t)((kt + 1) * 64 + row) * 512 + c8 * 8];
        vld[i] = *(const uint4*)&vbase[(size_t)row * 2048 + (kt + 1) * 64 + c8 * 8];
      }
    }

    // S^T = K @ Q^T : sacc[nf][r] = S[q=lr][key = nf*16 + lg*4 + r]
    f32x4 sacc[4];
#pragma unroll
    for (int j = 0; j < 4; ++j) {
      f32x4 zf = {0.f, 0.f, 0.f, 0.f};
      sacc[j] = zf;
    }
#pragma unroll
    for (int kf = 0; kf < 2; ++kf) {
#pragma unroll
      for (int nf = 0; nf < 4; ++nf) {
        int row = nf * 16 + lr;
        bf16x8 kb = *(const bf16x8*)&Ks[row][(kf * 32 + lg * 8) ^ ((row & 7) << 3)];
        sacc[nf] = mfma16(kb, qf[kf], sacc[nf]);
      }
    }

    // in-register tile max (16 values) + 2 shuffles across lg groups
    float mx0 = fmaxf(fmaxf(sacc[0][0], sacc[0][1]), fmaxf(sacc[0][2], sacc[0][3]));
    float mx1 = fmaxf(fmaxf(sacc[1][0], sacc[1][1]), fmaxf(sacc[1][2], sacc[1][3]));
    float mx2 = fmaxf(fmaxf(sacc[2][0], sacc[2][1]), fmaxf(sacc[2][2], sacc[2][3]));
    float mx3 = fmaxf(fmaxf(sacc[3][0], sacc[3][1]), fmaxf(sacc[3][2], sacc[3][3]));
    float mx = fmaxf(fmaxf(mx0, mx1), fmaxf(mx2, mx3));
    mx = fmaxf(mx, __shfl_xor(mx, 16));
    mx = fmaxf(mx, __shfl_xor(mx, 32));

    // defer-max (T13): rescale only when tile max exceeds running max + 8
    if (!__all(mx - m <= 8.f)) {
      float mnew = fmaxf(m, mx);
      float sc = __builtin_amdgcn_exp2f((m - mnew) * C);
      m = mnew;
      negmC = -m * C;
      l *= sc;
#pragma unroll
      for (int nfo = 0; nfo < 4; ++nfo)
#pragma unroll
        for (int r = 0; r < 4; ++r) oacc[nfo][r] *= sc;
    }

    // P = exp2(S*C - m*C), pack to bf16 pairs, store 8B per nf
    float rsum = 0.f;
#pragma unroll
    for (int nf = 0; nf < 4; ++nf) {
      float p0 = __builtin_amdgcn_exp2f(fmaf(sacc[nf][0], C, negmC));
      float p1 = __builtin_amdgcn_exp2f(fmaf(sacc[nf][1], C, negmC));
      float p2 = __builtin_amdgcn_exp2f(fmaf(sacc[nf][2], C, negmC));
      float p3 = __builtin_amdgcn_exp2f(fmaf(sacc[nf][3], C, negmC));
      rsum += (p0 + p1) + (p2 + p3);
      uint2 pw = make_uint2(cvtpk(p0, p1), cvtpk(p2, p3));
      *(uint2*)&Ps[w][lr][nf * 16 + lg * 4] = pw;
    }
    rsum += __shfl_xor(rsum, 16);
    rsum += __shfl_xor(rsum, 32);
    l += rsum;

    // wave-private P write->read ordering (rule #18)
    asm volatile("s_waitcnt lgkmcnt(0)" ::: "memory");
    __builtin_amdgcn_sched_barrier(0);

    // O^T += V^T @ P^T : oacc[nfo][r] = O[q=lr][d = nfo*16 + lg*4 + r]
#pragma unroll
    for (int ks = 0; ks < 2; ++ks) {
      bf16x8 pa = *(const bf16x8*)&Ps[w][lr][ks * 32 + lg * 8];
#pragma unroll
      for (int nfo = 0; nfo < 4; ++nfo) {
        int row = nfo * 16 + lr;
        bf16x8 vb = *(const bf16x8*)&Vs[row][(ks * 32 + lg * 8) ^ ((row & 7) << 3)];
        oacc[nfo] = mfma16(vb, pa, oacc[nfo]);
      }
    }
    __syncthreads();
  }

  // normalize + vectorized store: lane owns q = lr, 4 consecutive d per nfo
  float rl = 1.f / l;
#pragma unroll
  for (int nfo = 0; nfo < 4; ++nfo) {
    uint2 pw = make_uint2(cvtpk(oacc[nfo][0] * rl, oacc[nfo][1] * rl),
                          cvtpk(oacc[nfo][2] * rl, oacc[nfo][3] * rl));
    *(uint2*)&z[(qrow0 + lr) * 512 + h * 64 + nfo * 16 + lg * 4] = pw;
  }
}

extern "C" void kernel_launch(void* const* d_in, const int* in_sizes, int n_in,
                              void* d_out, int out_size, void* d_ws, size_t ws_size,
                              hipStream_t stream) {
  const float* Q  = (const float*)d_in[0];
  const float* K  = (const float*)d_in[1];
  const float* V  = (const float*)d_in[2];
  const float* Wq = (const float*)d_in[3];
  const float* bq = (const float*)d_in[4];
  const float* Wk = (const float*)d_in[5];
  const float* bk = (const float*)d_in[6];
  const float* Wv = (const float*)d_in[7];
  const float* bv = (const float*)d_in[8];
  const float* Wo = (const float*)d_in[9];
  const float* bo = (const float*)d_in[10];
  float* out = (float*)d_out;

  u16* ws  = (u16*)d_ws;
  u16* Wt  = ws;                                   // 4 x 512*512 (q,k,v,o)
  u16* qws = Wt + 4 * 262144;                      // 8192*512 each (q,k,vT consecutive)
  u16* vTw = qws + (size_t)2 * 8192 * 512;
  u16* zws = qws + (size_t)3 * 8192 * 512;

  wtrans_k<<<dim3(1024, 4), 256, 0, stream>>>(Wq, Wk, Wv, Wo, Wt);
  qkv_k<<<dim3(256, 3), 256, 0, stream>>>(Q, K, V, Wt, bq, bk, bv, qws);
  attn_k<<<1024, 256, 0, stream>>>(qws, qws + (size_t)8192 * 512, vTw, zws);
  gemm_out_k<<<256, 256, 0, stream>>>(zws, Wt + 3 * 262144, bo, out);
}

// Round 6
// 219.478 us; speedup vs baseline: 1.0002x; 1.0002x over previous
//
#include <hip/hip_runtime.h>

// MHA: B=4, S=2048, D_MODEL=512, H=8, D_HEAD=64
// Wt transpose -> QKV proj GEMMs (one launch) -> flash attn (swapped-MFMA,
// in-register softmax, defer-max, V-prefetch) -> out proj GEMM
// NOTE: attn staging/sync structure is r3's PROVEN one (single-buffer, 2 barriers,
// fence+sched_barrier before P reads). Only change vs r3: V B-fragments are
// prefetched before the softmax chain so the pinned region is 2 LDS reads, not 10.

typedef unsigned short u16;
typedef __bf16 bf16x8 __attribute__((ext_vector_type(8)));
typedef float  f32x4  __attribute__((ext_vector_type(4)));

__device__ __forceinline__ u16 f2bf(float x) {
  unsigned u = __float_as_uint(x);
  u += 0x7fffu + ((u >> 16) & 1u);   // RNE
  return (u16)(u >> 16);
}

__device__ __forceinline__ unsigned cvtpk(float lo, float hi) {
  unsigned r;
  asm("v_cvt_pk_bf16_f32 %0, %1, %2" : "=v"(r) : "v"(lo), "v"(hi));
  return r;
}

__device__ __forceinline__ f32x4 mfma16(bf16x8 a, bf16x8 b, f32x4 c) {
  return __builtin_amdgcn_mfma_f32_16x16x32_bf16(a, b, c, 0, 0, 0);
}

// ---- W[k][n] fp32 -> Wt[n][k] bf16, all 4 weights in one launch ----
__global__ __launch_bounds__(256) void wtrans_k(const float* __restrict__ W0,
                                                const float* __restrict__ W1,
                                                const float* __restrict__ W2,
                                                const float* __restrict__ W3,
                                                u16* __restrict__ Wt) {
  int sel = blockIdx.y;
  const float* W = sel == 0 ? W0 : sel == 1 ? W1 : sel == 2 ? W2 : W3;
  int idx = blockIdx.x * 256 + threadIdx.x;
  int k = idx >> 9, n = idx & 511;
  Wt[sel * 262144 + n * 512 + k] = f2bf(W[idx]);
}

// ---- GEMM body: A[8192x512] @ Bt^T + bias (Bt is [n][k] bf16) ----
// OUT_MODE: 0 bf16 [m][n], 1 bf16 vT[(b*8+h)*64+d][s], 2 fp32 [m][n]
template <bool A_BF16, int OUT_MODE>
__device__ __forceinline__ void gemm_body(const void* __restrict__ Ap,
                                          const u16* __restrict__ Bt,
                                          const float* __restrict__ bias,
                                          void* __restrict__ outp, int bidx) {
  __shared__ __align__(16) u16 As[128][72];
  __shared__ __align__(16) u16 Bs[128][72];
  int tid = threadIdx.x;
  int lane = tid & 63, wid = tid >> 6;
  int wm = wid >> 1, wn = wid & 1;
  int lr = lane & 15, lg = lane >> 4;
  int bm = bidx >> 2, bn = bidx & 3;

  f32x4 acc[4][4];
#pragma unroll
  for (int i = 0; i < 4; ++i)
#pragma unroll
    for (int j = 0; j < 4; ++j) {
      f32x4 z = {0.f, 0.f, 0.f, 0.f};
      acc[i][j] = z;
    }

  for (int kt = 0; kt < 8; ++kt) {
    int k0 = kt * 64;
    if (!A_BF16) {
      const float* A = (const float*)Ap;
#pragma unroll
      for (int i = 0; i < 8; ++i) {
        int idx = i * 256 + tid;
        int row = idx >> 4, c4 = idx & 15;
        float4 v = *(const float4*)(A + (size_t)(bm * 128 + row) * 512 + k0 + c4 * 4);
        ushort4 pk = make_ushort4(f2bf(v.x), f2bf(v.y), f2bf(v.z), f2bf(v.w));
        *(ushort4*)&As[row][c4 * 4] = pk;
      }
    } else {
      const u16* A = (const u16*)Ap;
#pragma unroll
      for (int i = 0; i < 4; ++i) {
        int idx = i * 256 + tid;
        int row = idx >> 3, c8 = idx & 7;
        uint4 v = *(const uint4*)(A + (size_t)(bm * 128 + row) * 512 + k0 + c8 * 8);
        *(uint4*)&As[row][c8 * 8] = v;
      }
    }
#pragma unroll
    for (int i = 0; i < 4; ++i) {
      int idx = i * 256 + tid;
      int row = idx >> 3, c8 = idx & 7;
      uint4 v = *(const uint4*)(Bt + (size_t)(bn * 128 + row) * 512 + k0 + c8 * 8);
      *(uint4*)&Bs[row][c8 * 8] = v;
    }
    __syncthreads();
#pragma unroll
    for (int kk = 0; kk < 2; ++kk) {
      bf16x8 af[4], bfr[4];
#pragma unroll
      for (int mf = 0; mf < 4; ++mf)
        af[mf] = *(const bf16x8*)&As[wm * 64 + mf * 16 + lr][kk * 32 + lg * 8];
#pragma unroll
      for (int nf = 0; nf < 4; ++nf)
        bfr[nf] = *(const bf16x8*)&Bs[wn * 64 + nf * 16 + lr][kk * 32 + lg * 8];
#pragma unroll
      for (int mf = 0; mf < 4; ++mf)
#pragma unroll
        for (int nf = 0; nf < 4; ++nf)
          acc[mf][nf] = mfma16(af[mf], bfr[nf], acc[mf][nf]);
    }
    __syncthreads();
  }

#pragma unroll
  for (int mf = 0; mf < 4; ++mf) {
#pragma unroll
    for (int nf = 0; nf < 4; ++nf) {
      int m = bm * 128 + wm * 64 + mf * 16 + lg * 4;
      int n = bn * 128 + wn * 64 + nf * 16 + lr;
      float bia = bias[n];
      if (OUT_MODE == 0) {
        u16* o = (u16*)outp;
#pragma unroll
        for (int r = 0; r < 4; ++r)
          o[(size_t)(m + r) * 512 + n] = f2bf(acc[mf][nf][r] + bia);
      } else if (OUT_MODE == 2) {
        float* o = (float*)outp;
#pragma unroll
        for (int r = 0; r < 4; ++r)
          o[(size_t)(m + r) * 512 + n] = acc[mf][nf][r] + bia;
      } else {
        u16* o = (u16*)outp;
        int b = m >> 11, s = m & 2047;
        int h = n >> 6, d = n & 63;
        ushort4 pk = make_ushort4(f2bf(acc[mf][nf][0] + bia), f2bf(acc[mf][nf][1] + bia),
                                  f2bf(acc[mf][nf][2] + bia), f2bf(acc[mf][nf][3] + bia));
        *(ushort4*)&o[(size_t)((b * 8 + h) * 64 + d) * 2048 + s] = pk;
      }
    }
  }
}

// QKV projections in one launch: blockIdx.y selects Q/K/V
__global__ __launch_bounds__(256) void qkv_k(const float* __restrict__ Q,
                                             const float* __restrict__ K,
                                             const float* __restrict__ V,
                                             const u16* __restrict__ Wt,
                                             const float* __restrict__ bq,
                                             const float* __restrict__ bk,
                                             const float* __restrict__ bv,
                                             u16* __restrict__ outbase) {
  int sel = blockIdx.y;
  const float* A = sel == 0 ? Q : sel == 1 ? K : V;
  const float* bia = sel == 0 ? bq : sel == 1 ? bk : bv;
  const u16* Bt = Wt + (size_t)sel * 262144;
  u16* out = outbase + (size_t)sel * 8192 * 512;
  if (sel == 2)
    gemm_body<false, 1>(A, Bt, bia, out, blockIdx.x);
  else
    gemm_body<false, 0>(A, Bt, bia, out, blockIdx.x);
}

__global__ __launch_bounds__(256) void gemm_out_k(const void* __restrict__ Ap,
                                                  const u16* __restrict__ Bt,
                                                  const float* __restrict__ bias,
                                                  void* __restrict__ outp) {
  gemm_body<true, 2>(Ap, Bt, bias, outp, blockIdx.x);
}

// ---- flash attention, r3-proven structure + V-prefetch ----
// S^T = mfma(K,Q): lane owns q = lane&15, keys nf*16+lg*4+r -> in-register softmax.
// O^T = mfma(V,P): oacc q-index = lane&15 too -> per-lane m/l, no shuffles.
__global__ __launch_bounds__(256, 4) void attn_k(const u16* __restrict__ q,
                                                 const u16* __restrict__ kmat,
                                                 const u16* __restrict__ vT,
                                                 u16* __restrict__ z) {
  __shared__ __align__(16) u16 Ks[64][64];      // [key][d], XOR swizzled
  __shared__ __align__(16) u16 Vs[64][64];      // [d][key], XOR swizzled
  __shared__ __align__(16) u16 Ps[4][16][72];   // per-wave P[q][key], padded stride
  const float C = 0.125f * 1.44269504f;         // 1/sqrt(64) * log2(e)
  int tid = threadIdx.x;
  int lane = tid & 63, w = tid >> 6;
  int lr = lane & 15, lg = lane >> 4;
  int bh = blockIdx.x >> 5, qt = blockIdx.x & 31;
  int b = bh >> 3, h = bh & 7;
  size_t qrow0 = (size_t)(b * 2048 + qt * 64 + w * 16);

  // Q as B-fragment: lane holds Q[q=lr][d = kf*32 + lg*8 + j]
  bf16x8 qf[2];
#pragma unroll
  for (int kf = 0; kf < 2; ++kf)
    qf[kf] = *(const bf16x8*)&q[(qrow0 + lr) * 512 + h * 64 + kf * 32 + lg * 8];

  f32x4 oacc[4];
#pragma unroll
  for (int j = 0; j < 4; ++j) {
    f32x4 zf = {0.f, 0.f, 0.f, 0.f};
    oacc[j] = zf;
  }
  float m = -1e30f, l = 0.f, negmC = 0.f;

  const u16* kbase = kmat + (size_t)(b * 2048) * 512 + h * 64;
  const u16* vbase = vT + (size_t)(bh * 64) * 2048;

  // staging registers (load early, ds_write at loop top)
  uint4 kld[2], vld[2];
#pragma unroll
  for (int i = 0; i < 2; ++i) {
    int idx = i * 256 + tid;
    int row = idx >> 3, c8 = idx & 7;
    kld[i] = *(const uint4*)&kbase[(size_t)row * 512 + c8 * 8];
    vld[i] = *(const uint4*)&vbase[(size_t)row * 2048 + c8 * 8];
  }

  for (int kt = 0; kt < 32; ++kt) {
    // write staged tile
#pragma unroll
    for (int i = 0; i < 2; ++i) {
      int idx = i * 256 + tid;
      int row = idx >> 3, c8 = idx & 7;
      int sc = (c8 * 8) ^ ((row & 7) << 3);
      *(uint4*)&Ks[row][sc] = kld[i];
      *(uint4*)&Vs[row][sc] = vld[i];
    }
    __syncthreads();
    // issue next tile's loads
    if (kt < 31) {
#pragma unroll
      for (int i = 0; i < 2; ++i) {
        int idx = i * 256 + tid;
        int row = idx >> 3, c8 = idx & 7;
        kld[i] = *(const uint4*)&kbase[(size_t)((kt + 1) * 64 + row) * 512 + c8 * 8];
        vld[i] = *(const uint4*)&vbase[(size_t)row * 2048 + (kt + 1) * 64 + c8 * 8];
      }
    }

    // S^T = K @ Q^T : sacc[nf][r] = S[q=lr][key = nf*16 + lg*4 + r]
    f32x4 sacc[4];
#pragma unroll
    for (int j = 0; j < 4; ++j) {
      f32x4 zf = {0.f, 0.f, 0.f, 0.f};
      sacc[j] = zf;
    }
#pragma unroll
    for (int kf = 0; kf < 2; ++kf) {
#pragma unroll
      for (int nf = 0; nf < 4; ++nf) {
        int row = nf * 16 + lr;
        bf16x8 kb = *(const bf16x8*)&Ks[row][(kf * 32 + lg * 8) ^ ((row & 7) << 3)];
        sacc[nf] = mfma16(kb, qf[kf], sacc[nf]);
      }
    }

    // V B-fragment prefetch (depends only on Vs staging, not on P):
    // hoisted in SOURCE order so the fence+sched_barrier below pins only P reads.
    bf16x8 vb[2][4];
#pragma unroll
    for (int ks = 0; ks < 2; ++ks)
#pragma unroll
      for (int nfo = 0; nfo < 4; ++nfo) {
        int row = nfo * 16 + lr;
        vb[ks][nfo] = *(const bf16x8*)&Vs[row][(ks * 32 + lg * 8) ^ ((row & 7) << 3)];
      }

    // in-register tile max + 2 shuffles across lg groups
    float mx0 = fmaxf(fmaxf(sacc[0][0], sacc[0][1]), fmaxf(sacc[0][2], sacc[0][3]));
    float mx1 = fmaxf(fmaxf(sacc[1][0], sacc[1][1]), fmaxf(sacc[1][2], sacc[1][3]));
    float mx2 = fmaxf(fmaxf(sacc[2][0], sacc[2][1]), fmaxf(sacc[2][2], sacc[2][3]));
    float mx3 = fmaxf(fmaxf(sacc[3][0], sacc[3][1]), fmaxf(sacc[3][2], sacc[3][3]));
    float mx = fmaxf(fmaxf(mx0, mx1), fmaxf(mx2, mx3));
    mx = fmaxf(mx, __shfl_xor(mx, 16));
    mx = fmaxf(mx, __shfl_xor(mx, 32));

    // defer-max (T13): rescale only when tile max exceeds running max + 8
    if (!__all(mx - m <= 8.f)) {
      float mnew = fmaxf(m, mx);
      float sc = __builtin_amdgcn_exp2f((m - mnew) * C);
      m = mnew;
      negmC = -m * C;
      l *= sc;
#pragma unroll
      for (int nfo = 0; nfo < 4; ++nfo)
#pragma unroll
        for (int r = 0; r < 4; ++r) oacc[nfo][r] *= sc;
    }

    // P = exp2(S*C - m*C), pack to bf16 pairs, store 8B per nf
    float rsum = 0.f;
#pragma unroll
    for (int nf = 0; nf < 4; ++nf) {
      float p0 = __builtin_amdgcn_exp2f(fmaf(sacc[nf][0], C, negmC));
      float p1 = __builtin_amdgcn_exp2f(fmaf(sacc[nf][1], C, negmC));
      float p2 = __builtin_amdgcn_exp2f(fmaf(sacc[nf][2], C, negmC));
      float p3 = __builtin_amdgcn_exp2f(fmaf(sacc[nf][3], C, negmC));
      rsum += (p0 + p1) + (p2 + p3);
      uint2 pw = make_uint2(cvtpk(p0, p1), cvtpk(p2, p3));
      *(uint2*)&Ps[w][lr][nf * 16 + lg * 4] = pw;
    }
    rsum += __shfl_xor(rsum, 16);
    rsum += __shfl_xor(rsum, 32);
    l += rsum;

    // P write->read ordering: r3-proven fence pair. Only the 2 Ps reads are pinned.
    asm volatile("s_waitcnt lgkmcnt(0)" ::: "memory");
    __builtin_amdgcn_sched_barrier(0);

    // O^T += V^T @ P^T : oacc[nfo][r] = O[q=lr][d = nfo*16 + lg*4 + r]
#pragma unroll
    for (int ks = 0; ks < 2; ++ks) {
      bf16x8 pa = *(const bf16x8*)&Ps[w][lr][ks * 32 + lg * 8];
#pragma unroll
      for (int nfo = 0; nfo < 4; ++nfo)
        oacc[nfo] = mfma16(vb[ks][nfo], pa, oacc[nfo]);
    }
    __syncthreads();
  }

  // normalize + vectorized store: lane owns q = lr, 4 consecutive d per nfo
  float rl = 1.f / l;
#pragma unroll
  for (int nfo = 0; nfo < 4; ++nfo) {
    uint2 pw = make_uint2(cvtpk(oacc[nfo][0] * rl, oacc[nfo][1] * rl),
                          cvtpk(oacc[nfo][2] * rl, oacc[nfo][3] * rl));
    *(uint2*)&z[(qrow0 + lr) * 512 + h * 64 + nfo * 16 + lg * 4] = pw;
  }
}

extern "C" void kernel_launch(void* const* d_in, const int* in_sizes, int n_in,
                              void* d_out, int out_size, void* d_ws, size_t ws_size,
                              hipStream_t stream) {
  const float* Q  = (const float*)d_in[0];
  const float* K  = (const float*)d_in[1];
  const float* V  = (const float*)d_in[2];
  const float* Wq = (const float*)d_in[3];
  const float* bq = (const float*)d_in[4];
  const float* Wk = (const float*)d_in[5];
  const float* bk = (const float*)d_in[6];
  const float* Wv = (const float*)d_in[7];
  const float* bv = (const float*)d_in[8];
  const float* Wo = (const float*)d_in[9];
  const float* bo = (const float*)d_in[10];
  float* out = (float*)d_out;

  u16* ws  = (u16*)d_ws;
  u16* Wt  = ws;                                   // 4 x 512*512 (q,k,v,o)
  u16* qws = Wt + 4 * 262144;                      // 8192*512 each (q,k,vT consecutive)
  u16* vTw = qws + (size_t)2 * 8192 * 512;
  u16* zws = qws + (size_t)3 * 8192 * 512;

  wtrans_k<<<dim3(1024, 4), 256, 0, stream>>>(Wq, Wk, Wv, Wo, Wt);
  qkv_k<<<dim3(256, 3), 256, 0, stream>>>(Q, K, V, Wt, bq, bk, bv, qws);
  attn_k<<<1024, 256, 0, stream>>>(qws, qws + (size_t)8192 * 512, vTw, zws);
  gemm_out_k<<<256, 256, 0, stream>>>(zws, Wt + 3 * 262144, bo, out);
}

// Round 7
// 159.175 us; speedup vs baseline: 1.3792x; 1.3788x over previous
//
#include <hip/hip_runtime.h>

// MHA: B=4, S=2048, D_MODEL=512, H=8, D_HEAD=64
// Wt transpose -> QKV proj GEMMs (one launch) -> flash attn -> out proj GEMM
// attn = r2's memory structure (direct global->LDS staging, no cross-barrier
// register arrays, plain launch_bounds -- zero scratch spill) + r6's compute
// structure (swapped MFMA, in-register softmax, defer-max, cvtpk, V-prefetch).
// r3..r6 lesson: __launch_bounds__(256,4) + register-staged tiles => 425 MB/dispatch
// scratch writeback (WRITE_SIZE counter), attn HBM-write-bound at 3.2 TB/s.

typedef unsigned short u16;
typedef __bf16 bf16x8 __attribute__((ext_vector_type(8)));
typedef float  f32x4  __attribute__((ext_vector_type(4)));

__device__ __forceinline__ u16 f2bf(float x) {
  unsigned u = __float_as_uint(x);
  u += 0x7fffu + ((u >> 16) & 1u);   // RNE
  return (u16)(u >> 16);
}

__device__ __forceinline__ unsigned cvtpk(float lo, float hi) {
  unsigned r;
  asm("v_cvt_pk_bf16_f32 %0, %1, %2" : "=v"(r) : "v"(lo), "v"(hi));
  return r;
}

__device__ __forceinline__ f32x4 mfma16(bf16x8 a, bf16x8 b, f32x4 c) {
  return __builtin_amdgcn_mfma_f32_16x16x32_bf16(a, b, c, 0, 0, 0);
}

// ---- W[k][n] fp32 -> Wt[n][k] bf16, all 4 weights in one launch ----
__global__ __launch_bounds__(256) void wtrans_k(const float* __restrict__ W0,
                                                const float* __restrict__ W1,
                                                const float* __restrict__ W2,
                                                const float* __restrict__ W3,
                                                u16* __restrict__ Wt) {
  int sel = blockIdx.y;
  const float* W = sel == 0 ? W0 : sel == 1 ? W1 : sel == 2 ? W2 : W3;
  int idx = blockIdx.x * 256 + threadIdx.x;
  int k = idx >> 9, n = idx & 511;
  Wt[sel * 262144 + n * 512 + k] = f2bf(W[idx]);
}

// ---- GEMM body: A[8192x512] @ Bt^T + bias (Bt is [n][k] bf16) ----
// OUT_MODE: 0 bf16 [m][n], 1 bf16 vT[(b*8+h)*64+d][s], 2 fp32 [m][n]
template <bool A_BF16, int OUT_MODE>
__device__ __forceinline__ void gemm_body(const void* __restrict__ Ap,
                                          const u16* __restrict__ Bt,
                                          const float* __restrict__ bias,
                                          void* __restrict__ outp, int bidx) {
  __shared__ __align__(16) u16 As[128][72];
  __shared__ __align__(16) u16 Bs[128][72];
  int tid = threadIdx.x;
  int lane = tid & 63, wid = tid >> 6;
  int wm = wid >> 1, wn = wid & 1;
  int lr = lane & 15, lg = lane >> 4;
  int bm = bidx >> 2, bn = bidx & 3;

  f32x4 acc[4][4];
#pragma unroll
  for (int i = 0; i < 4; ++i)
#pragma unroll
    for (int j = 0; j < 4; ++j) {
      f32x4 z = {0.f, 0.f, 0.f, 0.f};
      acc[i][j] = z;
    }

  for (int kt = 0; kt < 8; ++kt) {
    int k0 = kt * 64;
    if (!A_BF16) {
      const float* A = (const float*)Ap;
#pragma unroll
      for (int i = 0; i < 8; ++i) {
        int idx = i * 256 + tid;
        int row = idx >> 4, c4 = idx & 15;
        float4 v = *(const float4*)(A + (size_t)(bm * 128 + row) * 512 + k0 + c4 * 4);
        ushort4 pk = make_ushort4(f2bf(v.x), f2bf(v.y), f2bf(v.z), f2bf(v.w));
        *(ushort4*)&As[row][c4 * 4] = pk;
      }
    } else {
      const u16* A = (const u16*)Ap;
#pragma unroll
      for (int i = 0; i < 4; ++i) {
        int idx = i * 256 + tid;
        int row = idx >> 3, c8 = idx & 7;
        uint4 v = *(const uint4*)(A + (size_t)(bm * 128 + row) * 512 + k0 + c8 * 8);
        *(uint4*)&As[row][c8 * 8] = v;
      }
    }
#pragma unroll
    for (int i = 0; i < 4; ++i) {
      int idx = i * 256 + tid;
      int row = idx >> 3, c8 = idx & 7;
      uint4 v = *(const uint4*)(Bt + (size_t)(bn * 128 + row) * 512 + k0 + c8 * 8);
      *(uint4*)&Bs[row][c8 * 8] = v;
    }
    __syncthreads();
#pragma unroll
    for (int kk = 0; kk < 2; ++kk) {
      bf16x8 af[4], bfr[4];
#pragma unroll
      for (int mf = 0; mf < 4; ++mf)
        af[mf] = *(const bf16x8*)&As[wm * 64 + mf * 16 + lr][kk * 32 + lg * 8];
#pragma unroll
      for (int nf = 0; nf < 4; ++nf)
        bfr[nf] = *(const bf16x8*)&Bs[wn * 64 + nf * 16 + lr][kk * 32 + lg * 8];
#pragma unroll
      for (int mf = 0; mf < 4; ++mf)
#pragma unroll
        for (int nf = 0; nf < 4; ++nf)
          acc[mf][nf] = mfma16(af[mf], bfr[nf], acc[mf][nf]);
    }
    __syncthreads();
  }

#pragma unroll
  for (int mf = 0; mf < 4; ++mf) {
#pragma unroll
    for (int nf = 0; nf < 4; ++nf) {
      int m = bm * 128 + wm * 64 + mf * 16 + lg * 4;
      int n = bn * 128 + wn * 64 + nf * 16 + lr;
      float bia = bias[n];
      if (OUT_MODE == 0) {
        u16* o = (u16*)outp;
#pragma unroll
        for (int r = 0; r < 4; ++r)
          o[(size_t)(m + r) * 512 + n] = f2bf(acc[mf][nf][r] + bia);
      } else if (OUT_MODE == 2) {
        float* o = (float*)outp;
#pragma unroll
        for (int r = 0; r < 4; ++r)
          o[(size_t)(m + r) * 512 + n] = acc[mf][nf][r] + bia;
      } else {
        u16* o = (u16*)outp;
        int b = m >> 11, s = m & 2047;
        int h = n >> 6, d = n & 63;
        ushort4 pk = make_ushort4(f2bf(acc[mf][nf][0] + bia), f2bf(acc[mf][nf][1] + bia),
                                  f2bf(acc[mf][nf][2] + bia), f2bf(acc[mf][nf][3] + bia));
        *(ushort4*)&o[(size_t)((b * 8 + h) * 64 + d) * 2048 + s] = pk;
      }
    }
  }
}

// QKV projections in one launch: blockIdx.y selects Q/K/V
__global__ __launch_bounds__(256) void qkv_k(const float* __restrict__ Q,
                                             const float* __restrict__ K,
                                             const float* __restrict__ V,
                                             const u16* __restrict__ Wt,
                                             const float* __restrict__ bq,
                                             const float* __restrict__ bk,
                                             const float* __restrict__ bv,
                                             u16* __restrict__ outbase) {
  int sel = blockIdx.y;
  const float* A = sel == 0 ? Q : sel == 1 ? K : V;
  const float* bia = sel == 0 ? bq : sel == 1 ? bk : bv;
  const u16* Bt = Wt + (size_t)sel * 262144;
  u16* out = outbase + (size_t)sel * 8192 * 512;
  if (sel == 2)
    gemm_body<false, 1>(A, Bt, bia, out, blockIdx.x);
  else
    gemm_body<false, 0>(A, Bt, bia, out, blockIdx.x);
}

__global__ __launch_bounds__(256) void gemm_out_k(const void* __restrict__ Ap,
                                                  const u16* __restrict__ Bt,
                                                  const float* __restrict__ bias,
                                                  void* __restrict__ outp) {
  gemm_body<true, 2>(Ap, Bt, bias, outp, blockIdx.x);
}

// ---- flash attention ----
// S^T = mfma(K,Q): lane owns q = lane&15, keys nf*16+lg*4+r -> in-register softmax.
// O^T = mfma(V,P): oacc q-index = lane&15 too -> per-lane m/l, no shuffles.
// Staging: DIRECT global->LDS copy each tile (r2 structure, no spill).
__global__ __launch_bounds__(256) void attn_k(const u16* __restrict__ q,
                                              const u16* __restrict__ kmat,
                                              const u16* __restrict__ vT,
                                              u16* __restrict__ z) {
  __shared__ __align__(16) u16 Ks[64][64];      // [key][d], XOR swizzled
  __shared__ __align__(16) u16 Vs[64][64];      // [d][key], XOR swizzled
  __shared__ __align__(16) u16 Ps[4][16][72];   // per-wave P[q][key], padded stride
  const float C = 0.125f * 1.44269504f;         // 1/sqrt(64) * log2(e)
  int tid = threadIdx.x;
  int lane = tid & 63, w = tid >> 6;
  int lr = lane & 15, lg = lane >> 4;
  int bh = blockIdx.x >> 5, qt = blockIdx.x & 31;
  int b = bh >> 3, h = bh & 7;
  size_t qrow0 = (size_t)(b * 2048 + qt * 64 + w * 16);

  // Q as B-fragment: lane holds Q[q=lr][d = kf*32 + lg*8 + j]
  bf16x8 qf[2];
#pragma unroll
  for (int kf = 0; kf < 2; ++kf)
    qf[kf] = *(const bf16x8*)&q[(qrow0 + lr) * 512 + h * 64 + kf * 32 + lg * 8];

  f32x4 oacc[4];
#pragma unroll
  for (int j = 0; j < 4; ++j) {
    f32x4 zf = {0.f, 0.f, 0.f, 0.f};
    oacc[j] = zf;
  }
  float m = -1e30f, l = 0.f, negmC = 0.f;

  const u16* kbase = kmat + (size_t)(b * 2048) * 512 + h * 64;
  const u16* vbase = vT + (size_t)(bh * 64) * 2048;

  for (int kt = 0; kt < 32; ++kt) {
    // stage K tile [64 keys][64 d] and V tile [64 d][64 keys], swizzled,
    // direct global->LDS (short live ranges, no cross-barrier registers)
#pragma unroll
    for (int i = 0; i < 2; ++i) {
      int idx = i * 256 + tid;
      int row = idx >> 3, c8 = idx & 7;
      int sc = (c8 * 8) ^ ((row & 7) << 3);
      *(uint4*)&Ks[row][sc] = *(const uint4*)&kbase[(size_t)(kt * 64 + row) * 512 + c8 * 8];
      *(uint4*)&Vs[row][sc] = *(const uint4*)&vbase[(size_t)row * 2048 + kt * 64 + c8 * 8];
    }
    __syncthreads();

    // S^T = K @ Q^T : sacc[nf][r] = S[q=lr][key = nf*16 + lg*4 + r]
    f32x4 sacc[4];
#pragma unroll
    for (int j = 0; j < 4; ++j) {
      f32x4 zf = {0.f, 0.f, 0.f, 0.f};
      sacc[j] = zf;
    }
#pragma unroll
    for (int kf = 0; kf < 2; ++kf) {
#pragma unroll
      for (int nf = 0; nf < 4; ++nf) {
        int row = nf * 16 + lr;
        bf16x8 kb = *(const bf16x8*)&Ks[row][(kf * 32 + lg * 8) ^ ((row & 7) << 3)];
        sacc[nf] = mfma16(kb, qf[kf], sacc[nf]);
      }
    }

    // V B-fragment prefetch (independent of P) so the fenced region is small
    bf16x8 vb[2][4];
#pragma unroll
    for (int ks = 0; ks < 2; ++ks)
#pragma unroll
      for (int nfo = 0; nfo < 4; ++nfo) {
        int row = nfo * 16 + lr;
        vb[ks][nfo] = *(const bf16x8*)&Vs[row][(ks * 32 + lg * 8) ^ ((row & 7) << 3)];
      }

    // in-register tile max + 2 shuffles across lg groups
    float mx0 = fmaxf(fmaxf(sacc[0][0], sacc[0][1]), fmaxf(sacc[0][2], sacc[0][3]));
    float mx1 = fmaxf(fmaxf(sacc[1][0], sacc[1][1]), fmaxf(sacc[1][2], sacc[1][3]));
    float mx2 = fmaxf(fmaxf(sacc[2][0], sacc[2][1]), fmaxf(sacc[2][2], sacc[2][3]));
    float mx3 = fmaxf(fmaxf(sacc[3][0], sacc[3][1]), fmaxf(sacc[3][2], sacc[3][3]));
    float mx = fmaxf(fmaxf(mx0, mx1), fmaxf(mx2, mx3));
    mx = fmaxf(mx, __shfl_xor(mx, 16));
    mx = fmaxf(mx, __shfl_xor(mx, 32));

    // defer-max (T13): rescale only when tile max exceeds running max + 8
    if (!__all(mx - m <= 8.f)) {
      float mnew = fmaxf(m, mx);
      float sc = __builtin_amdgcn_exp2f((m - mnew) * C);
      m = mnew;
      negmC = -m * C;
      l *= sc;
#pragma unroll
      for (int nfo = 0; nfo < 4; ++nfo)
#pragma unroll
        for (int r = 0; r < 4; ++r) oacc[nfo][r] *= sc;
    }

    // P = exp2(S*C - m*C), pack to bf16 pairs, store 8B per nf
    float rsum = 0.f;
#pragma unroll
    for (int nf = 0; nf < 4; ++nf) {
      float p0 = __builtin_amdgcn_exp2f(fmaf(sacc[nf][0], C, negmC));
      float p1 = __builtin_amdgcn_exp2f(fmaf(sacc[nf][1], C, negmC));
      float p2 = __builtin_amdgcn_exp2f(fmaf(sacc[nf][2], C, negmC));
      float p3 = __builtin_amdgcn_exp2f(fmaf(sacc[nf][3], C, negmC));
      rsum += (p0 + p1) + (p2 + p3);
      uint2 pw = make_uint2(cvtpk(p0, p1), cvtpk(p2, p3));
      *(uint2*)&Ps[w][lr][nf * 16 + lg * 4] = pw;
    }
    rsum += __shfl_xor(rsum, 16);
    rsum += __shfl_xor(rsum, 32);
    l += rsum;

    // P write->read ordering: proven fence pair (r3/r6); pins only the 2 Ps reads
    asm volatile("s_waitcnt lgkmcnt(0)" ::: "memory");
    __builtin_amdgcn_sched_barrier(0);

    // O^T += V^T @ P^T : oacc[nfo][r] = O[q=lr][d = nfo*16 + lg*4 + r]
#pragma unroll
    for (int ks = 0; ks < 2; ++ks) {
      bf16x8 pa = *(const bf16x8*)&Ps[w][lr][ks * 32 + lg * 8];
#pragma unroll
      for (int nfo = 0; nfo < 4; ++nfo)
        oacc[nfo] = mfma16(vb[ks][nfo], pa, oacc[nfo]);
    }
    __syncthreads();
  }

  // normalize + vectorized store: lane owns q = lr, 4 consecutive d per nfo
  float rl = 1.f / l;
#pragma unroll
  for (int nfo = 0; nfo < 4; ++nfo) {
    uint2 pw = make_uint2(cvtpk(oacc[nfo][0] * rl, oacc[nfo][1] * rl),
                          cvtpk(oacc[nfo][2] * rl, oacc[nfo][3] * rl));
    *(uint2*)&z[(qrow0 + lr) * 512 + h * 64 + nfo * 16 + lg * 4] = pw;
  }
}

extern "C" void kernel_launch(void* const* d_in, const int* in_sizes, int n_in,
                              void* d_out, int out_size, void* d_ws, size_t ws_size,
                              hipStream_t stream) {
  const float* Q  = (const float*)d_in[0];
  const float* K  = (const float*)d_in[1];
  const float* V  = (const float*)d_in[2];
  const float* Wq = (const float*)d_in[3];
  const float* bq = (const float*)d_in[4];
  const float* Wk = (const float*)d_in[5];
  const float* bk = (const float*)d_in[6];
  const float* Wv = (const float*)d_in[7];
  const float* bv = (const float*)d_in[8];
  const float* Wo = (const float*)d_in[9];
  const float* bo = (const float*)d_in[10];
  float* out = (float*)d_out;

  u16* ws  = (u16*)d_ws;
  u16* Wt  = ws;                                   // 4 x 512*512 (q,k,v,o)
  u16* qws = Wt + 4 * 262144;                      // 8192*512 each (q,k,vT consecutive)
  u16* vTw = qws + (size_t)2 * 8192 * 512;
  u16* zws = qws + (size_t)3 * 8192 * 512;

  wtrans_k<<<dim3(1024, 4), 256, 0, stream>>>(Wq, Wk, Wv, Wo, Wt);
  qkv_k<<<dim3(256, 3), 256, 0, stream>>>(Q, K, V, Wt, bq, bk, bv, qws);
  attn_k<<<1024, 256, 0, stream>>>(qws, qws + (size_t)8192 * 512, vTw, zws);
  gemm_out_k<<<256, 256, 0, stream>>>(zws, Wt + 3 * 262144, bo, out);
}

// Round 8
// 145.673 us; speedup vs baseline: 1.5070x; 1.0927x over previous
//
#include <hip/hip_runtime.h>

// MHA: B=4, S=2048, D_MODEL=512, H=8, D_HEAD=64
// Wt transpose -> QKV proj GEMMs (one launch) -> flash attn -> out proj GEMM
// attn r8: K/V staged via __builtin_amdgcn_global_load_lds (async, no VGPR
// round-trip -> no spill). K double-buffered, V single-buffered. Counted
// vmcnt(2) keeps the K prefetch in flight across the mid-tile barrier (T4).
// LDS linear dest + pre-swizzled global source + XOR on read (rule #21);
// content identical to r7's proven layout. Compute/softmax/Ps path = r7.

typedef unsigned short u16;
typedef __bf16 bf16x8 __attribute__((ext_vector_type(8)));
typedef float  f32x4  __attribute__((ext_vector_type(4)));

__device__ __forceinline__ u16 f2bf(float x) {
  unsigned u = __float_as_uint(x);
  u += 0x7fffu + ((u >> 16) & 1u);   // RNE
  return (u16)(u >> 16);
}

__device__ __forceinline__ unsigned cvtpk(float lo, float hi) {
  unsigned r;
  asm("v_cvt_pk_bf16_f32 %0, %1, %2" : "=v"(r) : "v"(lo), "v"(hi));
  return r;
}

__device__ __forceinline__ f32x4 mfma16(bf16x8 a, bf16x8 b, f32x4 c) {
  return __builtin_amdgcn_mfma_f32_16x16x32_bf16(a, b, c, 0, 0, 0);
}

// async 16B/lane global->LDS; lds dest must be wave-uniform base (HW adds lane*16)
__device__ __forceinline__ void gl16(const u16* g, u16* l) {
  __builtin_amdgcn_global_load_lds(
      (const __attribute__((address_space(1))) void*)g,
      (__attribute__((address_space(3))) void*)l, 16, 0, 0);
}

// ---- W[k][n] fp32 -> Wt[n][k] bf16, all 4 weights in one launch ----
__global__ __launch_bounds__(256) void wtrans_k(const float* __restrict__ W0,
                                                const float* __restrict__ W1,
                                                const float* __restrict__ W2,
                                                const float* __restrict__ W3,
                                                u16* __restrict__ Wt) {
  int sel = blockIdx.y;
  const float* W = sel == 0 ? W0 : sel == 1 ? W1 : sel == 2 ? W2 : W3;
  int idx = blockIdx.x * 256 + threadIdx.x;
  int k = idx >> 9, n = idx & 511;
  Wt[sel * 262144 + n * 512 + k] = f2bf(W[idx]);
}

// ---- GEMM body: A[8192x512] @ Bt^T + bias (Bt is [n][k] bf16) ----
// OUT_MODE: 0 bf16 [m][n], 1 bf16 vT[(b*8+h)*64+d][s], 2 fp32 [m][n]
template <bool A_BF16, int OUT_MODE>
__device__ __forceinline__ void gemm_body(const void* __restrict__ Ap,
                                          const u16* __restrict__ Bt,
                                          const float* __restrict__ bias,
                                          void* __restrict__ outp, int bidx) {
  __shared__ __align__(16) u16 As[128][72];
  __shared__ __align__(16) u16 Bs[128][72];
  int tid = threadIdx.x;
  int lane = tid & 63, wid = tid >> 6;
  int wm = wid >> 1, wn = wid & 1;
  int lr = lane & 15, lg = lane >> 4;
  int bm = bidx >> 2, bn = bidx & 3;

  f32x4 acc[4][4];
#pragma unroll
  for (int i = 0; i < 4; ++i)
#pragma unroll
    for (int j = 0; j < 4; ++j) {
      f32x4 z = {0.f, 0.f, 0.f, 0.f};
      acc[i][j] = z;
    }

  for (int kt = 0; kt < 8; ++kt) {
    int k0 = kt * 64;
    if (!A_BF16) {
      const float* A = (const float*)Ap;
#pragma unroll
      for (int i = 0; i < 8; ++i) {
        int idx = i * 256 + tid;
        int row = idx >> 4, c4 = idx & 15;
        float4 v = *(const float4*)(A + (size_t)(bm * 128 + row) * 512 + k0 + c4 * 4);
        ushort4 pk = make_ushort4(f2bf(v.x), f2bf(v.y), f2bf(v.z), f2bf(v.w));
        *(ushort4*)&As[row][c4 * 4] = pk;
      }
    } else {
      const u16* A = (const u16*)Ap;
#pragma unroll
      for (int i = 0; i < 4; ++i) {
        int idx = i * 256 + tid;
        int row = idx >> 3, c8 = idx & 7;
        uint4 v = *(const uint4*)(A + (size_t)(bm * 128 + row) * 512 + k0 + c8 * 8);
        *(uint4*)&As[row][c8 * 8] = v;
      }
    }
#pragma unroll
    for (int i = 0; i < 4; ++i) {
      int idx = i * 256 + tid;
      int row = idx >> 3, c8 = idx & 7;
      uint4 v = *(const uint4*)(Bt + (size_t)(bn * 128 + row) * 512 + k0 + c8 * 8);
      *(uint4*)&Bs[row][c8 * 8] = v;
    }
    __syncthreads();
#pragma unroll
    for (int kk = 0; kk < 2; ++kk) {
      bf16x8 af[4], bfr[4];
#pragma unroll
      for (int mf = 0; mf < 4; ++mf)
        af[mf] = *(const bf16x8*)&As[wm * 64 + mf * 16 + lr][kk * 32 + lg * 8];
#pragma unroll
      for (int nf = 0; nf < 4; ++nf)
        bfr[nf] = *(const bf16x8*)&Bs[wn * 64 + nf * 16 + lr][kk * 32 + lg * 8];
#pragma unroll
      for (int mf = 0; mf < 4; ++mf)
#pragma unroll
        for (int nf = 0; nf < 4; ++nf)
          acc[mf][nf] = mfma16(af[mf], bfr[nf], acc[mf][nf]);
    }
    __syncthreads();
  }

#pragma unroll
  for (int mf = 0; mf < 4; ++mf) {
#pragma unroll
    for (int nf = 0; nf < 4; ++nf) {
      int m = bm * 128 + wm * 64 + mf * 16 + lg * 4;
      int n = bn * 128 + wn * 64 + nf * 16 + lr;
      float bia = bias[n];
      if (OUT_MODE == 0) {
        u16* o = (u16*)outp;
#pragma unroll
        for (int r = 0; r < 4; ++r)
          o[(size_t)(m + r) * 512 + n] = f2bf(acc[mf][nf][r] + bia);
      } else if (OUT_MODE == 2) {
        float* o = (float*)outp;
#pragma unroll
        for (int r = 0; r < 4; ++r)
          o[(size_t)(m + r) * 512 + n] = acc[mf][nf][r] + bia;
      } else {
        u16* o = (u16*)outp;
        int b = m >> 11, s = m & 2047;
        int h = n >> 6, d = n & 63;
        ushort4 pk = make_ushort4(f2bf(acc[mf][nf][0] + bia), f2bf(acc[mf][nf][1] + bia),
                                  f2bf(acc[mf][nf][2] + bia), f2bf(acc[mf][nf][3] + bia));
        *(ushort4*)&o[(size_t)((b * 8 + h) * 64 + d) * 2048 + s] = pk;
      }
    }
  }
}

// QKV projections in one launch: blockIdx.y selects Q/K/V
__global__ __launch_bounds__(256) void qkv_k(const float* __restrict__ Q,
                                             const float* __restrict__ K,
                                             const float* __restrict__ V,
                                             const u16* __restrict__ Wt,
                                             const float* __restrict__ bq,
                                             const float* __restrict__ bk,
                                             const float* __restrict__ bv,
                                             u16* __restrict__ outbase) {
  int sel = blockIdx.y;
  const float* A = sel == 0 ? Q : sel == 1 ? K : V;
  const float* bia = sel == 0 ? bq : sel == 1 ? bk : bv;
  const u16* Bt = Wt + (size_t)sel * 262144;
  u16* out = outbase + (size_t)sel * 8192 * 512;
  if (sel == 2)
    gemm_body<false, 1>(A, Bt, bia, out, blockIdx.x);
  else
    gemm_body<false, 0>(A, Bt, bia, out, blockIdx.x);
}

__global__ __launch_bounds__(256) void gemm_out_k(const void* __restrict__ Ap,
                                                  const u16* __restrict__ Bt,
                                                  const float* __restrict__ bias,
                                                  void* __restrict__ outp) {
  gemm_body<true, 2>(Ap, Bt, bias, outp, blockIdx.x);
}

// ---- flash attention ----
// S^T = mfma(K,Q): lane owns q = lane&15, keys nf*16+lg*4+r -> in-register softmax.
// O^T = mfma(V,P): oacc q-index = lane&15 too -> per-lane m/l, no shuffles.
// K/V staging: global_load_lds, K dbuf / V single, counted vmcnt.
__global__ __launch_bounds__(256) void attn_k(const u16* __restrict__ q,
                                              const u16* __restrict__ kmat,
                                              const u16* __restrict__ vT,
                                              u16* __restrict__ z) {
  __shared__ __align__(16) u16 Ks[2][64][64];   // [buf][key][d], swizzled content
  __shared__ __align__(16) u16 Vs[64][64];      // [d][key], swizzled content
  __shared__ __align__(16) u16 Ps[4][16][72];   // per-wave P[q][key] (r7-identical)
  const float C = 0.125f * 1.44269504f;         // 1/sqrt(64) * log2(e)
  int tid = threadIdx.x;
  int lane = tid & 63, w = tid >> 6;
  int lr = lane & 15, lg = lane >> 4;
  int bh = blockIdx.x >> 5, qt = blockIdx.x & 31;
  int b = bh >> 3, h = bh & 7;
  size_t qrow0 = (size_t)(b * 2048 + qt * 64 + w * 16);

  // Q as B-fragment: lane holds Q[q=lr][d = kf*32 + lg*8 + j]
  bf16x8 qf[2];
#pragma unroll
  for (int kf = 0; kf < 2; ++kf)
    qf[kf] = *(const bf16x8*)&q[(qrow0 + lr) * 512 + h * 64 + kf * 32 + lg * 8];

  f32x4 oacc[4];
#pragma unroll
  for (int j = 0; j < 4; ++j) {
    f32x4 zf = {0.f, 0.f, 0.f, 0.f};
    oacc[j] = zf;
  }
  float m = -1e30f, l = 0.f, negmC = 0.f;

  const u16* kbase = kmat + (size_t)(b * 2048) * 512 + h * 64;
  const u16* vbase = vT + (size_t)(bh * 64) * 2048;

  // staging coords: lane covers LDS idx = i*256 + tid; row = idx>>3, c8dst = idx&7.
  // Pre-swizzled SOURCE column: c8src = c8dst ^ (row&7)  (row&7 == (tid>>3)&7 for both i)
  int r0 = tid >> 3;                         // 0..31
  int c8s = (tid & 7) ^ (r0 & 7);
  // prologue: K(0) -> buf0 (lds dest per wave: (i*256 + w*64) u16x8 chunks)
  gl16(&kbase[(size_t)r0 * 512 + c8s * 8],        &Ks[0][0][0] + w * 512);
  gl16(&kbase[(size_t)(r0 + 32) * 512 + c8s * 8], &Ks[0][0][0] + 2048 + w * 512);
  __syncthreads();

  for (int kt = 0; kt < 32; ++kt) {
    int cur = kt & 1;
    // issue V(kt) (waited mid-tile via vmcnt), then K(kt+1) (stays in flight)
    gl16(&vbase[(size_t)r0 * 2048 + kt * 64 + c8s * 8],        &Vs[0][0] + w * 512);
    gl16(&vbase[(size_t)(r0 + 32) * 2048 + kt * 64 + c8s * 8], &Vs[0][0] + 2048 + w * 512);
    if (kt < 31) {
      u16* KL = &Ks[cur ^ 1][0][0];
      gl16(&kbase[(size_t)((kt + 1) * 64 + r0) * 512 + c8s * 8],        KL + w * 512);
      gl16(&kbase[(size_t)((kt + 1) * 64 + r0 + 32) * 512 + c8s * 8],  KL + 2048 + w * 512);
    }

    // S^T = K @ Q^T : sacc[nf][r] = S[q=lr][key = nf*16 + lg*4 + r]
    f32x4 sacc[4];
#pragma unroll
    for (int j = 0; j < 4; ++j) {
      f32x4 zf = {0.f, 0.f, 0.f, 0.f};
      sacc[j] = zf;
    }
#pragma unroll
    for (int kf = 0; kf < 2; ++kf) {
#pragma unroll
      for (int nf = 0; nf < 4; ++nf) {
        int row = nf * 16 + lr;
        bf16x8 kb = *(const bf16x8*)&Ks[cur][row][(kf * 32 + lg * 8) ^ ((row & 7) << 3)];
        sacc[nf] = mfma16(kb, qf[kf], sacc[nf]);
      }
    }

    // in-register tile max + 2 shuffles across lg groups
    float mx0 = fmaxf(fmaxf(sacc[0][0], sacc[0][1]), fmaxf(sacc[0][2], sacc[0][3]));
    float mx1 = fmaxf(fmaxf(sacc[1][0], sacc[1][1]), fmaxf(sacc[1][2], sacc[1][3]));
    float mx2 = fmaxf(fmaxf(sacc[2][0], sacc[2][1]), fmaxf(sacc[2][2], sacc[2][3]));
    float mx3 = fmaxf(fmaxf(sacc[3][0], sacc[3][1]), fmaxf(sacc[3][2], sacc[3][3]));
    float mx = fmaxf(fmaxf(mx0, mx1), fmaxf(mx2, mx3));
    mx = fmaxf(mx, __shfl_xor(mx, 16));
    mx = fmaxf(mx, __shfl_xor(mx, 32));

    // defer-max (T13): rescale only when tile max exceeds running max + 8
    if (!__all(mx - m <= 8.f)) {
      float mnew = fmaxf(m, mx);
      float sc = __builtin_amdgcn_exp2f((m - mnew) * C);
      m = mnew;
      negmC = -m * C;
      l *= sc;
#pragma unroll
      for (int nfo = 0; nfo < 4; ++nfo)
#pragma unroll
        for (int r = 0; r < 4; ++r) oacc[nfo][r] *= sc;
    }

    // P = exp2(S*C - m*C), pack to bf16 pairs, store 8B per nf (r7-identical)
    float rsum = 0.f;
#pragma unroll
    for (int nf = 0; nf < 4; ++nf) {
      float p0 = __builtin_amdgcn_exp2f(fmaf(sacc[nf][0], C, negmC));
      float p1 = __builtin_amdgcn_exp2f(fmaf(sacc[nf][1], C, negmC));
      float p2 = __builtin_amdgcn_exp2f(fmaf(sacc[nf][2], C, negmC));
      float p3 = __builtin_amdgcn_exp2f(fmaf(sacc[nf][3], C, negmC));
      rsum += (p0 + p1) + (p2 + p3);
      uint2 pw = make_uint2(cvtpk(p0, p1), cvtpk(p2, p3));
      *(uint2*)&Ps[w][lr][nf * 16 + lg * 4] = pw;
    }
    rsum += __shfl_xor(rsum, 16);
    rsum += __shfl_xor(rsum, 32);
    l += rsum;

    // order Ps writes before Ps reads; wait V(kt) landed (counted: K prefetch
    // stays in flight); barrier makes all waves' V chunks visible.
    asm volatile("s_waitcnt lgkmcnt(0)" ::: "memory");
    if (kt < 31) {
      asm volatile("s_waitcnt vmcnt(2)" ::: "memory");
    } else {
      asm volatile("s_waitcnt vmcnt(0)" ::: "memory");
    }
    __builtin_amdgcn_s_barrier();

    // O^T += V^T @ P^T : oacc[nfo][r] = O[q=lr][d = nfo*16 + lg*4 + r]
#pragma unroll
    for (int ks = 0; ks < 2; ++ks) {
      bf16x8 pa = *(const bf16x8*)&Ps[w][lr][ks * 32 + lg * 8];
#pragma unroll
      for (int nfo = 0; nfo < 4; ++nfo) {
        int row = nfo * 16 + lr;
        bf16x8 vbr = *(const bf16x8*)&Vs[row][(ks * 32 + lg * 8) ^ ((row & 7) << 3)];
        oacc[nfo] = mfma16(vbr, pa, oacc[nfo]);
      }
    }
    // end of tile: drain K(kt+1) (vmcnt0+lgkm0+barrier) so next QK^T is safe,
    // and protect Vs/Ps reuse.
    __syncthreads();
  }

  // normalize + vectorized store: lane owns q = lr, 4 consecutive d per nfo
  float rl = 1.f / l;
#pragma unroll
  for (int nfo = 0; nfo < 4; ++nfo) {
    uint2 pw = make_uint2(cvtpk(oacc[nfo][0] * rl, oacc[nfo][1] * rl),
                          cvtpk(oacc[nfo][2] * rl, oacc[nfo][3] * rl));
    *(uint2*)&z[(qrow0 + lr) * 512 + h * 64 + nfo * 16 + lg * 4] = pw;
  }
}

extern "C" void kernel_launch(void* const* d_in, const int* in_sizes, int n_in,
                              void* d_out, int out_size, void* d_ws, size_t ws_size,
                              hipStream_t stream) {
  const float* Q  = (const float*)d_in[0];
  const float* K  = (const float*)d_in[1];
  const float* V  = (const float*)d_in[2];
  const float* Wq = (const float*)d_in[3];
  const float* bq = (const float*)d_in[4];
  const float* Wk = (const float*)d_in[5];
  const float* bk = (const float*)d_in[6];
  const float* Wv = (const float*)d_in[7];
  const float* bv = (const float*)d_in[8];
  const float* Wo = (const float*)d_in[9];
  const float* bo = (const float*)d_in[10];
  float* out = (float*)d_out;

  u16* ws  = (u16*)d_ws;
  u16* Wt  = ws;                                   // 4 x 512*512 (q,k,v,o)
  u16* qws = Wt + 4 * 262144;                      // 8192*512 each (q,k,vT consecutive)
  u16* vTw = qws + (size_t)2 * 8192 * 512;
  u16* zws = qws + (size_t)3 * 8192 * 512;

  wtrans_k<<<dim3(1024, 4), 256, 0, stream>>>(Wq, Wk, Wv, Wo, Wt);
  qkv_k<<<dim3(256, 3), 256, 0, stream>>>(Q, K, V, Wt, bq, bk, bv, qws);
  attn_k<<<1024, 256, 0, stream>>>(qws, qws + (size_t)8192 * 512, vTw, zws);
  gemm_out_k<<<256, 256, 0, stream>>>(zws, Wt + 3 * 262144, bo, out);
}